// Round 1
// baseline (1714.385 us; speedup 1.0000x reference)
//
#include <hip/hip_runtime.h>
#include <hip/hip_bf16.h>
#include <math.h>

typedef __bf16 bf16x8_t __attribute__((ext_vector_type(8)));
typedef float f32x4_t __attribute__((ext_vector_type(4)));
using bf16 = __hip_bfloat16;

#define EPS_RMS 1.1920929e-07f

__device__ __forceinline__ float silu_f(float v) { return v / (1.0f + __expf(-v)); }

__device__ __forceinline__ void gl2lds16(const bf16* g, bf16* l) {
    __builtin_amdgcn_global_load_lds(
        (__attribute__((address_space(1))) void*)(g),
        (__attribute__((address_space(3))) void*)(l), 16, 0, 0);
}

// ---------------------------------------------------------------------------
// GEMM: C[M,N] = A[M,K] @ B[N,K]^T, A/B bf16, fp32 accumulate.
// 128x128 tile, BK=32, 4 waves each computing 64x64 via 4x4 frags of 16x16x32.
// Double-buffered LDS: per K-step {barrier -> issue next-tile gl2lds -> compute}.
// __syncthreads() == vmcnt(0)+lgkmcnt(0)+barrier, so prefetch latency is hidden
// under the current tile's ds_read+MFMA and only one barrier per K-step.
// EPI: 0 = silu(acc+bias) -> bf16 Hout[M,N]
//      1 = (acc+bias) scatter -> Wbuf (16 matrices of 1024x1024 bf16)
//      2 = X[row,col] += 0.1*acc          (X fp32, ld = N)
//      3 = X[row,col] += 0.1*silu(acc)
//      4 = X[row,col]  = acc (fp32 out, ld = N)
// ---------------------------------------------------------------------------
#define BM 128
#define BN 128
#define BKK 32
#define ASZ (BM * BKK)
#define BSZ (BN * BKK)

template<int EPI>
__global__ __launch_bounds__(256) void gemm_bt(
    const bf16* __restrict__ A, const bf16* __restrict__ B,
    int M, int N, int K,
    const float* __restrict__ bias,
    float* __restrict__ X,
    bf16* __restrict__ Hout)
{
    __shared__ bf16 sA[2 * ASZ];
    __shared__ bf16 sB[2 * BSZ];
    const int tid  = threadIdx.x;
    const int wave = tid >> 6;
    const int lane = tid & 63;
    const int quad = lane >> 4;
    const int l16  = lane & 15;
    const int wm   = (wave >> 1) * 64;
    const int wn   = (wave & 1) * 64;
    const int m0   = blockIdx.y * BM;
    const int n0   = blockIdx.x * BN;

    // staging map: chunk = 16 rows (1KB); wave handles chunks 2w, 2w+1.
    // lane l -> row (l>>2) within chunk, elem offset (l&3)*8 within 64B row.
    const int ar = lane >> 2;
    const int ac = (lane & 3) * 8;
    const int c0 = wave * 2, c1 = wave * 2 + 1;

    const bf16* a0 = A + (size_t)(m0 + c0 * 16 + ar) * K + ac;
    const bf16* a1 = A + (size_t)(m0 + c1 * 16 + ar) * K + ac;
    const bf16* b0 = B + (size_t)(n0 + c0 * 16 + ar) * K + ac;
    const bf16* b1 = B + (size_t)(n0 + c1 * 16 + ar) * K + ac;
    bf16* sA0 = sA + c0 * 16 * BKK;
    bf16* sA1 = sA + c1 * 16 * BKK;
    bf16* sB0 = sB + c0 * 16 * BKK;
    bf16* sB1 = sB + c1 * 16 * BKK;

    f32x4_t acc[4][4];
#pragma unroll
    for (int i = 0; i < 4; i++)
#pragma unroll
        for (int j = 0; j < 4; j++) acc[i][j] = (f32x4_t){0.f, 0.f, 0.f, 0.f};

    const int NT = K / BKK;
    // prologue: stage tile 0 into buffer 0
    gl2lds16(a0, sA0);
    gl2lds16(a1, sA1);
    gl2lds16(b0, sB0);
    gl2lds16(b1, sB1);

    int cur = 0;
    for (int t = 0; t < NT; ++t) {
        __syncthreads();   // buf[cur] staged (vmcnt 0) + prev reads of buf[cur^1] done
        if (t + 1 < NT) {
            const int k1 = (t + 1) * BKK;
            const int nb = (cur ^ 1);
            gl2lds16(a0 + k1, sA0 + nb * ASZ);
            gl2lds16(a1 + k1, sA1 + nb * ASZ);
            gl2lds16(b0 + k1, sB0 + nb * BSZ);
            gl2lds16(b1 + k1, sB1 + nb * BSZ);
        }
        const bf16* rA = sA + cur * ASZ;
        const bf16* rB = sB + cur * BSZ;
        bf16x8_t af[4], bfr[4];
#pragma unroll
        for (int mi = 0; mi < 4; mi++)
            af[mi] = *reinterpret_cast<const bf16x8_t*>(&rA[(wm + mi * 16 + l16) * BKK + quad * 8]);
#pragma unroll
        for (int ni = 0; ni < 4; ni++)
            bfr[ni] = *reinterpret_cast<const bf16x8_t*>(&rB[(wn + ni * 16 + l16) * BKK + quad * 8]);
#pragma unroll
        for (int mi = 0; mi < 4; mi++)
#pragma unroll
            for (int ni = 0; ni < 4; ni++)
                acc[mi][ni] = __builtin_amdgcn_mfma_f32_16x16x32_bf16(af[mi], bfr[ni], acc[mi][ni], 0, 0, 0);
        cur ^= 1;
    }

#pragma unroll
    for (int mi = 0; mi < 4; mi++) {
#pragma unroll
        for (int ni = 0; ni < 4; ni++) {
#pragma unroll
            for (int r = 0; r < 4; r++) {
                const int row = m0 + wm + mi * 16 + quad * 4 + r;  // M index
                const int col = n0 + wn + ni * 16 + l16;           // N index
                float v = acc[mi][ni][r];
                if (EPI == 0) {
                    v += bias[col];
                    Hout[(size_t)row * N + col] = __float2bfloat16(silu_f(v));
                } else if (EPI == 1) {
                    v += bias[col];
                    const int g  = row >> 12;       // matrix 0..15
                    const int rc = row & 4095;
                    const int rr = rc >> 6, cc = rc & 63;
                    const int ii = col >> 4, jj = col & 15;
                    Hout[((size_t)g << 20) + (size_t)(rr * 16 + ii) * 1024 + cc * 16 + jj] =
                        __float2bfloat16(v);
                } else if (EPI == 2) {
                    const size_t idx = (size_t)row * N + col;
                    X[idx] = X[idx] + 0.1f * v;
                } else if (EPI == 3) {
                    const size_t idx = (size_t)row * N + col;
                    X[idx] = X[idx] + 0.1f * silu_f(v);
                } else {
                    X[(size_t)row * N + col] = v;
                }
            }
        }
    }
}

// ---------------------------------------------------------------------------
// Layer-GEMM variant: 64x128 tile (grid 8x64 = 512 blocks -> 2 blocks/CU
// instead of 1, so barrier-residual latency is filled by the co-resident
// block's MFMA). 4 waves in 2x2 layout, each computing 32x64 (2x4 frags).
// Same double-buffered 2-phase pipeline. EPI 2/3 only.
// ---------------------------------------------------------------------------
#define SBM 64
#define SBN 128
#define SASZ (SBM * BKK)
#define SBSZ (SBN * BKK)

template<int EPI>
__global__ __launch_bounds__(256) void gemm_bt_sm(
    const bf16* __restrict__ A, const bf16* __restrict__ B,
    int M, int N, int K,
    float* __restrict__ X)
{
    __shared__ bf16 sA[2 * SASZ];
    __shared__ bf16 sB[2 * SBSZ];
    const int tid  = threadIdx.x;
    const int wave = tid >> 6;
    const int lane = tid & 63;
    const int quad = lane >> 4;
    const int l16  = lane & 15;
    const int wm   = (wave >> 1) * 32;
    const int wn   = (wave & 1) * 64;
    const int m0   = blockIdx.y * SBM;
    const int n0   = blockIdx.x * SBN;

    // staging: A = 4 chunks of 1KB (wave w takes chunk w);
    //          B = 8 chunks (wave w takes 2w, 2w+1). 3 gl2lds per thread.
    const int ar = lane >> 2;
    const int ac = (lane & 3) * 8;

    const bf16* aP = A + (size_t)(m0 + wave * 16 + ar) * K + ac;
    const bf16* b0 = B + (size_t)(n0 + (wave * 2) * 16 + ar) * K + ac;
    const bf16* b1 = B + (size_t)(n0 + (wave * 2 + 1) * 16 + ar) * K + ac;
    bf16* sAw = sA + wave * 16 * BKK;
    bf16* sB0 = sB + (wave * 2) * 16 * BKK;
    bf16* sB1 = sB + (wave * 2 + 1) * 16 * BKK;

    f32x4_t acc[2][4];
#pragma unroll
    for (int i = 0; i < 2; i++)
#pragma unroll
        for (int j = 0; j < 4; j++) acc[i][j] = (f32x4_t){0.f, 0.f, 0.f, 0.f};

    const int NT = K / BKK;
    gl2lds16(aP, sAw);
    gl2lds16(b0, sB0);
    gl2lds16(b1, sB1);

    int cur = 0;
    for (int t = 0; t < NT; ++t) {
        __syncthreads();
        if (t + 1 < NT) {
            const int k1 = (t + 1) * BKK;
            const int nb = (cur ^ 1);
            gl2lds16(aP + k1, sAw + nb * SASZ);
            gl2lds16(b0 + k1, sB0 + nb * SBSZ);
            gl2lds16(b1 + k1, sB1 + nb * SBSZ);
        }
        const bf16* rA = sA + cur * SASZ;
        const bf16* rB = sB + cur * SBSZ;
        bf16x8_t af[2], bfr[4];
#pragma unroll
        for (int mi = 0; mi < 2; mi++)
            af[mi] = *reinterpret_cast<const bf16x8_t*>(&rA[(wm + mi * 16 + l16) * BKK + quad * 8]);
#pragma unroll
        for (int ni = 0; ni < 4; ni++)
            bfr[ni] = *reinterpret_cast<const bf16x8_t*>(&rB[(wn + ni * 16 + l16) * BKK + quad * 8]);
#pragma unroll
        for (int mi = 0; mi < 2; mi++)
#pragma unroll
            for (int ni = 0; ni < 4; ni++)
                acc[mi][ni] = __builtin_amdgcn_mfma_f32_16x16x32_bf16(af[mi], bfr[ni], acc[mi][ni], 0, 0, 0);
        cur ^= 1;
    }

#pragma unroll
    for (int mi = 0; mi < 2; mi++) {
#pragma unroll
        for (int ni = 0; ni < 4; ni++) {
#pragma unroll
            for (int r = 0; r < 4; r++) {
                const int row = m0 + wm + mi * 16 + quad * 4 + r;
                const int col = n0 + wn + ni * 16 + l16;
                const float v = acc[mi][ni][r];
                const size_t idx = (size_t)row * N + col;
                if (EPI == 3) X[idx] = X[idx] + 0.1f * silu_f(v);
                else          X[idx] = X[idx] + 0.1f * v;
            }
        }
    }
}

// ---------------------------------------------------------------------------
__global__ __launch_bounds__(256) void rmsnorm_k(const float* __restrict__ x,
                                                 const float* __restrict__ w,
                                                 bf16* __restrict__ h)
{
    const int row = blockIdx.x, tid = threadIdx.x;
    const float4 v = *reinterpret_cast<const float4*>(x + (size_t)row * 1024 + tid * 4);
    float ss = v.x * v.x + v.y * v.y + v.z * v.z + v.w * v.w;
#pragma unroll
    for (int off = 32; off > 0; off >>= 1) ss += __shfl_down(ss, off, 64);
    __shared__ float red[4];
    if ((tid & 63) == 0) red[tid >> 6] = ss;
    __syncthreads();
    const float total = red[0] + red[1] + red[2] + red[3];
    const float s = rsqrtf(total * (1.0f / 1024.0f) + EPS_RMS);
    const float4 wv = *reinterpret_cast<const float4*>(w + tid * 4);
    struct alignas(8) BH4 { bf16 a, b, c, d; } o;
    o.a = __float2bfloat16(v.x * s * wv.x);
    o.b = __float2bfloat16(v.y * s * wv.y);
    o.c = __float2bfloat16(v.z * s * wv.z);
    o.d = __float2bfloat16(v.w * s * wv.w);
    *reinterpret_cast<BH4*>(h + (size_t)row * 1024 + tid * 4) = o;
}

__global__ __launch_bounds__(256) void gather_k(const int* __restrict__ tokens,
                                                const float* __restrict__ embed,
                                                float* __restrict__ x)
{
    const int row = blockIdx.x, tid = threadIdx.x;
    const int tok = tokens[row];
    *reinterpret_cast<float4*>(x + (size_t)row * 1024 + tid * 4) =
        *reinterpret_cast<const float4*>(embed + (size_t)tok * 1024 + tid * 4);
}

__global__ __launch_bounds__(256) void cvt_bf16_k(const float* __restrict__ in,
                                                  bf16* __restrict__ out, long n4)
{
    const long i = (long)blockIdx.x * 256 + threadIdx.x;
    if (i >= n4) return;
    const float4 v = *reinterpret_cast<const float4*>(in + i * 4);
    struct alignas(8) BH4 { bf16 a, b, c, d; } o;
    o.a = __float2bfloat16(v.x);
    o.b = __float2bfloat16(v.y);
    o.c = __float2bfloat16(v.z);
    o.d = __float2bfloat16(v.w);
    *reinterpret_cast<BH4*>(out + i * 4) = o;
}

__global__ __launch_bounds__(256) void w0pad_k(const float* __restrict__ w0,
                                               bf16* __restrict__ w0p)
{
    const int t = blockIdx.x * 256 + threadIdx.x;   // 16384 = 256*64
    const int j = t >> 6, i = t & 63;
    const float v = (i < 52) ? w0[j * 52 + i] : 0.f;
    w0p[t] = __float2bfloat16(v);
}

// Enc[65536, 64]: row = g*4096 + r*64 + c  (g = li*2 + func), cols 0..51 encoded, 52..63 zero.
// torch cat order: [x(4), sin(2^0 pi x)(4), cos(2^0 pi x)(4), sin(2^1..)...]
__global__ __launch_bounds__(256) void encode_k(bf16* __restrict__ enc)
{
    const int t = blockIdx.x * 256 + threadIdx.x;   // 4,194,304 total
    const int row = t >> 6, col = t & 63;
    const int g = row >> 12;
    const int rc = row & 4095;
    const int r = rc >> 6, c = rc & 63;
    const int li = g >> 1;
    const float ft = (g & 1) ? 0.5f : 0.0f;
    const float coord[4] = { li * (1.0f / 7.0f), r * (1.0f / 63.0f), c * (1.0f / 63.0f), ft };
    float v = 0.f;
    if (col < 4) {
        v = coord[col];
    } else if (col < 52) {
        const int f = (col - 4) >> 3, rem = (col - 4) & 7;
        const float a = (float)(1 << f) * 3.14159265358979323846f * coord[rem & 3];
        v = (rem < 4) ? sinf(a) : cosf(a);
    }
    enc[t] = __float2bfloat16(v);
}

// ---------------------------------------------------------------------------
extern "C" void kernel_launch(void* const* d_in, const int* in_sizes, int n_in,
                              void* d_out, int out_size, void* d_ws, size_t ws_size,
                              hipStream_t stream)
{
    const int*   tokens       = (const int*)d_in[0];
    const float* embed        = (const float*)d_in[1];
    const float* lm_head_w    = (const float*)d_in[2];
    const float* final_norm_w = (const float*)d_in[3];
    const float* norm1_w      = (const float*)d_in[4];
    const float* norm2_w      = (const float*)d_in[5];
    const float* g_w0 = (const float*)d_in[6];
    const float* g_b0 = (const float*)d_in[7];
    const float* g_w1 = (const float*)d_in[8];
    const float* g_b1 = (const float*)d_in[9];
    const float* g_w2 = (const float*)d_in[10];
    const float* g_b2 = (const float*)d_in[11];
    const float* g_w3 = (const float*)d_in[12];
    const float* g_b3 = (const float*)d_in[13];
    float* out = (float*)d_out;

    char* ws = (char*)d_ws;
    size_t off = 0;
    auto alloc = [&](size_t bytes) -> void* {
        void* p = ws + off;
        off += (bytes + 255) & ~(size_t)255;
        return p;
    };
    bf16*  Wbuf = (bf16*)alloc((size_t)16 * 1024 * 1024 * 2);   // 16 x [1024,1024] bf16
    bf16*  lhb  = (bf16*)alloc((size_t)32000 * 1024 * 2);       // lm_head bf16
    bf16*  Enc  = (bf16*)alloc((size_t)65536 * 64 * 2);
    bf16*  HA   = (bf16*)alloc((size_t)65536 * 256 * 2);
    bf16*  HB   = (bf16*)alloc((size_t)65536 * 256 * 2);
    float* x    = (float*)alloc((size_t)4096 * 1024 * 4);
    bf16*  hb   = (bf16*)alloc((size_t)4096 * 1024 * 2);
    bf16*  w0p  = (bf16*)alloc((size_t)256 * 64 * 2);
    bf16*  w1b  = (bf16*)alloc((size_t)256 * 256 * 2);
    bf16*  w2b  = (bf16*)alloc((size_t)256 * 256 * 2);
    bf16*  w3b  = (bf16*)alloc((size_t)256 * 256 * 2);
    (void)in_sizes; (void)n_in; (void)out_size; (void)ws_size;

    // weight conversions + encoding
    cvt_bf16_k<<<64, 256, 0, stream>>>(g_w1, w1b, 16384);
    cvt_bf16_k<<<64, 256, 0, stream>>>(g_w2, w2b, 16384);
    cvt_bf16_k<<<64, 256, 0, stream>>>(g_w3, w3b, 16384);
    cvt_bf16_k<<<32000, 256, 0, stream>>>(lm_head_w, lhb, 8192000);
    w0pad_k<<<64, 256, 0, stream>>>(g_w0, w0p);
    encode_k<<<16384, 256, 0, stream>>>(Enc);

    // generator MLP as 4 batched GEMMs over all 16 matrices (M = 65536)
    gemm_bt<0><<<dim3(2, 512), 256, 0, stream>>>(Enc, w0p, 65536, 256, 64,  g_b0, nullptr, HA);
    gemm_bt<0><<<dim3(2, 512), 256, 0, stream>>>(HA,  w1b, 65536, 256, 256, g_b1, nullptr, HB);
    gemm_bt<0><<<dim3(2, 512), 256, 0, stream>>>(HB,  w2b, 65536, 256, 256, g_b2, nullptr, HA);
    gemm_bt<1><<<dim3(2, 512), 256, 0, stream>>>(HA,  w3b, 65536, 256, 256, g_b3, nullptr, Wbuf);

    // embed gather
    gather_k<<<4096, 256, 0, stream>>>(tokens, embed, x);

    // layers: 64x128-tile GEMM -> 512 blocks (2/CU) + dbuf pipeline
    for (int li = 0; li < 8; li++) {
        rmsnorm_k<<<4096, 256, 0, stream>>>(x, norm1_w + li * 1024, hb);
        gemm_bt_sm<2><<<dim3(8, 64), 256, 0, stream>>>(hb, Wbuf + ((size_t)(li * 2) << 20),
                                                       4096, 1024, 1024, x);
        rmsnorm_k<<<4096, 256, 0, stream>>>(x, norm2_w + li * 1024, hb);
        gemm_bt_sm<3><<<dim3(8, 64), 256, 0, stream>>>(hb, Wbuf + ((size_t)(li * 2 + 1) << 20),
                                                       4096, 1024, 1024, x);
    }

    // final norm + lm_head
    rmsnorm_k<<<4096, 256, 0, stream>>>(x, final_norm_w, hb);
    gemm_bt<4><<<dim3(250, 32), 256, 0, stream>>>(hb, lhb, 4096, 32000, 1024, nullptr, out, nullptr);
}

// Round 2
// 1568.985 us; speedup vs baseline: 1.0927x; 1.0927x over previous
//
#include <hip/hip_runtime.h>
#include <hip/hip_bf16.h>
#include <math.h>

typedef __bf16 bf16x8_t __attribute__((ext_vector_type(8)));
typedef float f32x4_t __attribute__((ext_vector_type(4)));
using bf16 = __hip_bfloat16;

#define EPS_RMS 1.1920929e-07f

__device__ __forceinline__ float silu_f(float v) { return v / (1.0f + __expf(-v)); }

__device__ __forceinline__ void gl2lds16(const bf16* g, bf16* l) {
    __builtin_amdgcn_global_load_lds(
        (__attribute__((address_space(1))) void*)(g),
        (__attribute__((address_space(3))) void*)(l), 16, 0, 0);
}

// ---------------------------------------------------------------------------
// GEMM: C[M,N] = A[M,K] @ B[N,K]^T, A/B bf16, fp32 accumulate.
// 128x128 tile, BK=32, 4 waves each computing 64x64 via 4x4 frags of 16x16x32.
// Double-buffered LDS: per K-step {barrier -> issue next-tile gl2lds -> compute}.
// EPI: 0 = silu(acc+bias) -> bf16 Hout[M,N]
//      1 = (acc+bias) scatter -> Wbuf (16 matrices of 1024x1024 bf16)
//      2 = X[row,col] += 0.1*acc          (X fp32, ld = N)
//      3 = X[row,col] += 0.1*silu(acc)
//      4 = X[row,col]  = acc (fp32 out, ld = N)
//          EPI 4 uses a 1D grid (multiple of 8) with M-major-within-panel
//          ordering + bijective XCD chunk swizzle: 32 consecutive blocks share
//          one 256KB B-panel and land on one XCD -> panel fetched ~once/XCD.
// ---------------------------------------------------------------------------
#define BM 128
#define BN 128
#define BKK 32
#define ASZ (BM * BKK)
#define BSZ (BN * BKK)

template<int EPI>
__global__ __launch_bounds__(256) void gemm_bt(
    const bf16* __restrict__ A, const bf16* __restrict__ B,
    int M, int N, int K,
    const float* __restrict__ bias,
    float* __restrict__ X,
    bf16* __restrict__ Hout)
{
    __shared__ bf16 sA[2 * ASZ];
    __shared__ bf16 sB[2 * BSZ];
    const int tid  = threadIdx.x;
    const int wave = tid >> 6;
    const int lane = tid & 63;
    const int quad = lane >> 4;
    const int l16  = lane & 15;
    const int wm   = (wave >> 1) * 64;
    const int wn   = (wave & 1) * 64;

    int m0, n0;
    if constexpr (EPI == 4) {
        // 1D grid, gridDim.x % 8 == 0. Bijective XCD chunk swizzle (m204 form
        // for nwg%8==0), then M-major decomposition (B-panel shared by
        // consecutive blocks).
        const int nwg = gridDim.x;
        const int q   = nwg >> 3;
        const int id  = blockIdx.x;
        const int wg  = (id & 7) * q + (id >> 3);
        const int mtiles = M >> 7;          // M / 128
        m0 = (wg % mtiles) * BM;
        n0 = (wg / mtiles) * BN;
    } else {
        m0 = blockIdx.y * BM;
        n0 = blockIdx.x * BN;
    }

    // staging map: chunk = 16 rows (1KB); wave handles chunks 2w, 2w+1.
    // lane l -> row (l>>2) within chunk, elem offset (l&3)*8 within 64B row.
    const int ar = lane >> 2;
    const int ac = (lane & 3) * 8;
    const int c0 = wave * 2, c1 = wave * 2 + 1;

    const bf16* a0 = A + (size_t)(m0 + c0 * 16 + ar) * K + ac;
    const bf16* a1 = A + (size_t)(m0 + c1 * 16 + ar) * K + ac;
    const bf16* b0 = B + (size_t)(n0 + c0 * 16 + ar) * K + ac;
    const bf16* b1 = B + (size_t)(n0 + c1 * 16 + ar) * K + ac;
    bf16* sA0 = sA + c0 * 16 * BKK;
    bf16* sA1 = sA + c1 * 16 * BKK;
    bf16* sB0 = sB + c0 * 16 * BKK;
    bf16* sB1 = sB + c1 * 16 * BKK;

    f32x4_t acc[4][4];
#pragma unroll
    for (int i = 0; i < 4; i++)
#pragma unroll
        for (int j = 0; j < 4; j++) acc[i][j] = (f32x4_t){0.f, 0.f, 0.f, 0.f};

    const int NT = K / BKK;
    gl2lds16(a0, sA0);
    gl2lds16(a1, sA1);
    gl2lds16(b0, sB0);
    gl2lds16(b1, sB1);

    int cur = 0;
    for (int t = 0; t < NT; ++t) {
        __syncthreads();   // buf[cur] staged (vmcnt 0) + prev reads of buf[cur^1] done
        if (t + 1 < NT) {
            const int k1 = (t + 1) * BKK;
            const int nb = (cur ^ 1);
            gl2lds16(a0 + k1, sA0 + nb * ASZ);
            gl2lds16(a1 + k1, sA1 + nb * ASZ);
            gl2lds16(b0 + k1, sB0 + nb * BSZ);
            gl2lds16(b1 + k1, sB1 + nb * BSZ);
        }
        const bf16* rA = sA + cur * ASZ;
        const bf16* rB = sB + cur * BSZ;
        bf16x8_t af[4], bfr[4];
#pragma unroll
        for (int mi = 0; mi < 4; mi++)
            af[mi] = *reinterpret_cast<const bf16x8_t*>(&rA[(wm + mi * 16 + l16) * BKK + quad * 8]);
#pragma unroll
        for (int ni = 0; ni < 4; ni++)
            bfr[ni] = *reinterpret_cast<const bf16x8_t*>(&rB[(wn + ni * 16 + l16) * BKK + quad * 8]);
#pragma unroll
        for (int mi = 0; mi < 4; mi++)
#pragma unroll
            for (int ni = 0; ni < 4; ni++)
                acc[mi][ni] = __builtin_amdgcn_mfma_f32_16x16x32_bf16(af[mi], bfr[ni], acc[mi][ni], 0, 0, 0);
        cur ^= 1;
    }

#pragma unroll
    for (int mi = 0; mi < 4; mi++) {
#pragma unroll
        for (int ni = 0; ni < 4; ni++) {
#pragma unroll
            for (int r = 0; r < 4; r++) {
                const int row = m0 + wm + mi * 16 + quad * 4 + r;  // M index
                const int col = n0 + wn + ni * 16 + l16;           // N index
                float v = acc[mi][ni][r];
                if (EPI == 0) {
                    v += bias[col];
                    Hout[(size_t)row * N + col] = __float2bfloat16(silu_f(v));
                } else if (EPI == 1) {
                    v += bias[col];
                    const int g  = row >> 12;       // matrix 0..15
                    const int rc = row & 4095;
                    const int rr = rc >> 6, cc = rc & 63;
                    const int ii = col >> 4, jj = col & 15;
                    Hout[((size_t)g << 20) + (size_t)(rr * 16 + ii) * 1024 + cc * 16 + jj] =
                        __float2bfloat16(v);
                } else if (EPI == 2) {
                    const size_t idx = (size_t)row * N + col;
                    X[idx] = X[idx] + 0.1f * v;
                } else if (EPI == 3) {
                    const size_t idx = (size_t)row * N + col;
                    X[idx] = X[idx] + 0.1f * silu_f(v);
                } else {
                    X[(size_t)row * N + col] = v;
                }
            }
        }
    }
}

// ---------------------------------------------------------------------------
// Layer-GEMM variant: 64x64 tile, grid 16x64 = 1024 blocks -> 4 blocks/CU,
// 16 waves/CU, so each block's barrier-drain stall is filled by co-resident
// blocks' MFMA (TLP latency hiding; no sync-structure change).
// 4 waves in 2x2 layout, each computing 32x32 (2x2 frags). EPI 2/3 only.
// ---------------------------------------------------------------------------
#define TBM 64
#define TBN 64
#define TSZ (TBM * BKK)

template<int EPI>
__global__ __launch_bounds__(256) void gemm_bt_64(
    const bf16* __restrict__ A, const bf16* __restrict__ B,
    int M, int N, int K,
    float* __restrict__ X)
{
    __shared__ bf16 sA[2 * TSZ];
    __shared__ bf16 sB[2 * TSZ];
    const int tid  = threadIdx.x;
    const int wave = tid >> 6;
    const int lane = tid & 63;
    const int quad = lane >> 4;
    const int l16  = lane & 15;
    const int wm   = (wave >> 1) * 32;
    const int wn   = (wave & 1) * 32;
    const int m0   = blockIdx.y * TBM;
    const int n0   = blockIdx.x * TBN;

    // staging: A = 4 chunks of 1KB (wave w takes chunk w); B likewise.
    const int ar = lane >> 2;
    const int ac = (lane & 3) * 8;

    const bf16* aP = A + (size_t)(m0 + wave * 16 + ar) * K + ac;
    const bf16* bP = B + (size_t)(n0 + wave * 16 + ar) * K + ac;
    bf16* sAw = sA + wave * 16 * BKK;
    bf16* sBw = sB + wave * 16 * BKK;

    f32x4_t acc[2][2];
#pragma unroll
    for (int i = 0; i < 2; i++)
#pragma unroll
        for (int j = 0; j < 2; j++) acc[i][j] = (f32x4_t){0.f, 0.f, 0.f, 0.f};

    const int NT = K / BKK;
    gl2lds16(aP, sAw);
    gl2lds16(bP, sBw);

    int cur = 0;
    for (int t = 0; t < NT; ++t) {
        __syncthreads();
        if (t + 1 < NT) {
            const int k1 = (t + 1) * BKK;
            const int nb = (cur ^ 1);
            gl2lds16(aP + k1, sAw + nb * TSZ);
            gl2lds16(bP + k1, sBw + nb * TSZ);
        }
        const bf16* rA = sA + cur * TSZ;
        const bf16* rB = sB + cur * TSZ;
        bf16x8_t af[2], bfr[2];
#pragma unroll
        for (int mi = 0; mi < 2; mi++)
            af[mi] = *reinterpret_cast<const bf16x8_t*>(&rA[(wm + mi * 16 + l16) * BKK + quad * 8]);
#pragma unroll
        for (int ni = 0; ni < 2; ni++)
            bfr[ni] = *reinterpret_cast<const bf16x8_t*>(&rB[(wn + ni * 16 + l16) * BKK + quad * 8]);
#pragma unroll
        for (int mi = 0; mi < 2; mi++)
#pragma unroll
            for (int ni = 0; ni < 2; ni++)
                acc[mi][ni] = __builtin_amdgcn_mfma_f32_16x16x32_bf16(af[mi], bfr[ni], acc[mi][ni], 0, 0, 0);
        cur ^= 1;
    }

#pragma unroll
    for (int mi = 0; mi < 2; mi++) {
#pragma unroll
        for (int ni = 0; ni < 2; ni++) {
#pragma unroll
            for (int r = 0; r < 4; r++) {
                const int row = m0 + wm + mi * 16 + quad * 4 + r;
                const int col = n0 + wn + ni * 16 + l16;
                const float v = acc[mi][ni][r];
                const size_t idx = (size_t)row * N + col;
                if (EPI == 3) X[idx] = X[idx] + 0.1f * silu_f(v);
                else          X[idx] = X[idx] + 0.1f * v;
            }
        }
    }
}

// ---------------------------------------------------------------------------
__global__ __launch_bounds__(256) void rmsnorm_k(const float* __restrict__ x,
                                                 const float* __restrict__ w,
                                                 bf16* __restrict__ h)
{
    const int row = blockIdx.x, tid = threadIdx.x;
    const float4 v = *reinterpret_cast<const float4*>(x + (size_t)row * 1024 + tid * 4);
    float ss = v.x * v.x + v.y * v.y + v.z * v.z + v.w * v.w;
#pragma unroll
    for (int off = 32; off > 0; off >>= 1) ss += __shfl_down(ss, off, 64);
    __shared__ float red[4];
    if ((tid & 63) == 0) red[tid >> 6] = ss;
    __syncthreads();
    const float total = red[0] + red[1] + red[2] + red[3];
    const float s = rsqrtf(total * (1.0f / 1024.0f) + EPS_RMS);
    const float4 wv = *reinterpret_cast<const float4*>(w + tid * 4);
    struct alignas(8) BH4 { bf16 a, b, c, d; } o;
    o.a = __float2bfloat16(v.x * s * wv.x);
    o.b = __float2bfloat16(v.y * s * wv.y);
    o.c = __float2bfloat16(v.z * s * wv.z);
    o.d = __float2bfloat16(v.w * s * wv.w);
    *reinterpret_cast<BH4*>(h + (size_t)row * 1024 + tid * 4) = o;
}

__global__ __launch_bounds__(256) void gather_k(const int* __restrict__ tokens,
                                                const float* __restrict__ embed,
                                                float* __restrict__ x)
{
    const int row = blockIdx.x, tid = threadIdx.x;
    const int tok = tokens[row];
    *reinterpret_cast<float4*>(x + (size_t)row * 1024 + tid * 4) =
        *reinterpret_cast<const float4*>(embed + (size_t)tok * 1024 + tid * 4);
}

__global__ __launch_bounds__(256) void cvt_bf16_k(const float* __restrict__ in,
                                                  bf16* __restrict__ out, long n4)
{
    const long i = (long)blockIdx.x * 256 + threadIdx.x;
    if (i >= n4) return;
    const float4 v = *reinterpret_cast<const float4*>(in + i * 4);
    struct alignas(8) BH4 { bf16 a, b, c, d; } o;
    o.a = __float2bfloat16(v.x);
    o.b = __float2bfloat16(v.y);
    o.c = __float2bfloat16(v.z);
    o.d = __float2bfloat16(v.w);
    *reinterpret_cast<BH4*>(out + i * 4) = o;
}

__global__ __launch_bounds__(256) void w0pad_k(const float* __restrict__ w0,
                                               bf16* __restrict__ w0p)
{
    const int t = blockIdx.x * 256 + threadIdx.x;   // 16384 = 256*64
    const int j = t >> 6, i = t & 63;
    const float v = (i < 52) ? w0[j * 52 + i] : 0.f;
    w0p[t] = __float2bfloat16(v);
}

// Enc[65536, 64]: row = g*4096 + r*64 + c  (g = li*2 + func), cols 0..51 encoded, 52..63 zero.
// torch cat order: [x(4), sin(2^0 pi x)(4), cos(2^0 pi x)(4), sin(2^1..)...]
__global__ __launch_bounds__(256) void encode_k(bf16* __restrict__ enc)
{
    const int t = blockIdx.x * 256 + threadIdx.x;   // 4,194,304 total
    const int row = t >> 6, col = t & 63;
    const int g = row >> 12;
    const int rc = row & 4095;
    const int r = rc >> 6, c = rc & 63;
    const int li = g >> 1;
    const float ft = (g & 1) ? 0.5f : 0.0f;
    const float coord[4] = { li * (1.0f / 7.0f), r * (1.0f / 63.0f), c * (1.0f / 63.0f), ft };
    float v = 0.f;
    if (col < 4) {
        v = coord[col];
    } else if (col < 52) {
        const int f = (col - 4) >> 3, rem = (col - 4) & 7;
        const float a = (float)(1 << f) * 3.14159265358979323846f * coord[rem & 3];
        v = (rem < 4) ? sinf(a) : cosf(a);
    }
    enc[t] = __float2bfloat16(v);
}

// ---------------------------------------------------------------------------
extern "C" void kernel_launch(void* const* d_in, const int* in_sizes, int n_in,
                              void* d_out, int out_size, void* d_ws, size_t ws_size,
                              hipStream_t stream)
{
    const int*   tokens       = (const int*)d_in[0];
    const float* embed        = (const float*)d_in[1];
    const float* lm_head_w    = (const float*)d_in[2];
    const float* final_norm_w = (const float*)d_in[3];
    const float* norm1_w      = (const float*)d_in[4];
    const float* norm2_w      = (const float*)d_in[5];
    const float* g_w0 = (const float*)d_in[6];
    const float* g_b0 = (const float*)d_in[7];
    const float* g_w1 = (const float*)d_in[8];
    const float* g_b1 = (const float*)d_in[9];
    const float* g_w2 = (const float*)d_in[10];
    const float* g_b2 = (const float*)d_in[11];
    const float* g_w3 = (const float*)d_in[12];
    const float* g_b3 = (const float*)d_in[13];
    float* out = (float*)d_out;

    char* ws = (char*)d_ws;
    size_t off = 0;
    auto alloc = [&](size_t bytes) -> void* {
        void* p = ws + off;
        off += (bytes + 255) & ~(size_t)255;
        return p;
    };
    bf16*  Wbuf = (bf16*)alloc((size_t)16 * 1024 * 1024 * 2);   // 16 x [1024,1024] bf16
    bf16*  lhb  = (bf16*)alloc((size_t)32000 * 1024 * 2);       // lm_head bf16
    bf16*  Enc  = (bf16*)alloc((size_t)65536 * 64 * 2);
    bf16*  HA   = (bf16*)alloc((size_t)65536 * 256 * 2);
    bf16*  HB   = (bf16*)alloc((size_t)65536 * 256 * 2);
    float* x    = (float*)alloc((size_t)4096 * 1024 * 4);
    bf16*  hb   = (bf16*)alloc((size_t)4096 * 1024 * 2);
    bf16*  w0p  = (bf16*)alloc((size_t)256 * 64 * 2);
    bf16*  w1b  = (bf16*)alloc((size_t)256 * 256 * 2);
    bf16*  w2b  = (bf16*)alloc((size_t)256 * 256 * 2);
    bf16*  w3b  = (bf16*)alloc((size_t)256 * 256 * 2);
    (void)in_sizes; (void)n_in; (void)out_size; (void)ws_size;

    // weight conversions + encoding
    cvt_bf16_k<<<64, 256, 0, stream>>>(g_w1, w1b, 16384);
    cvt_bf16_k<<<64, 256, 0, stream>>>(g_w2, w2b, 16384);
    cvt_bf16_k<<<64, 256, 0, stream>>>(g_w3, w3b, 16384);
    cvt_bf16_k<<<32000, 256, 0, stream>>>(lm_head_w, lhb, 8192000);
    w0pad_k<<<64, 256, 0, stream>>>(g_w0, w0p);
    encode_k<<<16384, 256, 0, stream>>>(Enc);

    // generator MLP as 4 batched GEMMs over all 16 matrices (M = 65536)
    gemm_bt<0><<<dim3(2, 512), 256, 0, stream>>>(Enc, w0p, 65536, 256, 64,  g_b0, nullptr, HA);
    gemm_bt<0><<<dim3(2, 512), 256, 0, stream>>>(HA,  w1b, 65536, 256, 256, g_b1, nullptr, HB);
    gemm_bt<0><<<dim3(2, 512), 256, 0, stream>>>(HB,  w2b, 65536, 256, 256, g_b2, nullptr, HA);
    gemm_bt<1><<<dim3(2, 512), 256, 0, stream>>>(HA,  w3b, 65536, 256, 256, g_b3, nullptr, Wbuf);

    // embed gather
    gather_k<<<4096, 256, 0, stream>>>(tokens, embed, x);

    // layers: 64x64-tile GEMM -> 1024 blocks (4/CU) for TLP latency hiding
    for (int li = 0; li < 8; li++) {
        rmsnorm_k<<<4096, 256, 0, stream>>>(x, norm1_w + li * 1024, hb);
        gemm_bt_64<2><<<dim3(16, 64), 256, 0, stream>>>(hb, Wbuf + ((size_t)(li * 2) << 20),
                                                        4096, 1024, 1024, x);
        rmsnorm_k<<<4096, 256, 0, stream>>>(x, norm2_w + li * 1024, hb);
        gemm_bt_64<3><<<dim3(16, 64), 256, 0, stream>>>(hb, Wbuf + ((size_t)(li * 2 + 1) << 20),
                                                        4096, 1024, 1024, x);
    }

    // final norm + lm_head: 1D grid 8000 blocks (32 M-tiles x 250 N-tiles),
    // M-major + XCD chunk swizzle inside the kernel (EPI 4 path).
    rmsnorm_k<<<4096, 256, 0, stream>>>(x, final_norm_w, hb);
    gemm_bt<4><<<dim3(8000), 256, 0, stream>>>(hb, lhb, 4096, 32000, 1024, nullptr, out, nullptr);
}